// Round 3
// baseline (296.624 us; speedup 1.0000x reference)
//
#include <hip/hip_runtime.h>
#include <math.h>

// out[m, n] = base[n] - pre_cls[n, idx[m]],  base[n] = sum_c softplus(pre_cls[n, c])
// M = N = 8192, C = 80.
//
// R3: FUSED single kernel, NO workspace writes.
// Post-mortem R2: top-5 dispatches were all fillBufferAligned writing 1 GB
// (the workspace re-poison) at ~170 us each. My two kernels can only account
// for <~105 us of the 276 us total (worst-case traffic 536 MB at 6.3 TB/s).
// => the timed region pays a ~170 us workspace re-poison because we wrote d_ws.
// Fix: build each block's slice Dt[c][n_local] = base[n]-pre[n][c] in LDS
// (84 KB) and stream it straight to out. One dispatch, pure write-bound.

#define CE_C 80
#define TN 256
#define TM 1024

typedef float v4f __attribute__((ext_vector_type(4)));

__device__ __forceinline__ float softplus_f(float x) {
    // logaddexp(x, 0) = max(x,0) + log1p(exp(-|x|))
    return fmaxf(x, 0.0f) + log1pf(expf(-fabsf(x)));
}

// grid (N/TN, M/TM), block 512.
// Phase 1: threads 0..255 compute base(n) for n = n0+t and fill Dt[80][256];
//          threads 256..511 stage idx[m0..m0+1023] into LDS.
// Phase 2: 512 iters; thread t writes out[m0+mi+(t>>8)][n0+(t&255)] = Dt[c][t&255].
__global__ __launch_bounds__(512) void ce_fused(const float* __restrict__ pre,
                                                const int* __restrict__ idx,
                                                float* __restrict__ out, int N) {
    __shared__ float Dt[CE_C][TN];   // 80 KB
    __shared__ int sidx[TM];         // 4 KB
    const int t = threadIdx.x;
    const int n0 = blockIdx.x * TN;
    const int m0 = blockIdx.y * TM;

    if (t < TN) {
        const float* row = pre + (size_t)(n0 + t) * CE_C;
        v4f v[20];
        float s = 0.0f;
#pragma unroll
        for (int j = 0; j < 20; ++j) {
            v[j] = *reinterpret_cast<const v4f*>(row + 4 * j);
            s += softplus_f(v[j].x) + softplus_f(v[j].y)
               + softplus_f(v[j].z) + softplus_f(v[j].w);
        }
#pragma unroll
        for (int j = 0; j < 20; ++j) {
            // lanes write consecutive LDS addresses -> conflict-free
            Dt[4 * j + 0][t] = s - v[j].x;
            Dt[4 * j + 1][t] = s - v[j].y;
            Dt[4 * j + 2][t] = s - v[j].z;
            Dt[4 * j + 3][t] = s - v[j].w;
        }
    } else {
        int i = t - TN;              // 0..255, each stages 4 idx values
        reinterpret_cast<int4*>(sidx)[i] =
            reinterpret_cast<const int4*>(idx + m0)[i];
    }
    __syncthreads();

    const int tn = t & (TN - 1);
    const int tm = t >> 8;           // 0 or 1: two output rows per iteration
    float* dst = out + (size_t)m0 * N + n0 + tn;
#pragma unroll 4
    for (int mi = 0; mi < TM; mi += 2) {
        int c = sidx[mi + tm];       // wave-uniform -> LDS broadcast
        float val = Dt[c][tn];       // consecutive lanes -> conflict-free
        __builtin_nontemporal_store(val, dst + (size_t)(mi + tm) * N);
    }
}

// ---- generic fallback (shape not multiple of tiles): no-workspace direct ----
__global__ void ce_base(const float* __restrict__ pre, float* __restrict__ base, int N) {
    int n = blockIdx.x * blockDim.x + threadIdx.x;
    if (n >= N) return;
    const float* row = pre + (size_t)n * CE_C;
    float b = 0.0f;
#pragma unroll
    for (int c = 0; c < CE_C; c += 4) {
        v4f v = *reinterpret_cast<const v4f*>(row + c);
        b += softplus_f(v.x) + softplus_f(v.y) + softplus_f(v.z) + softplus_f(v.w);
    }
    base[n] = b;
}

__global__ void ce_direct(const float* __restrict__ pre, const float* __restrict__ base,
                          const int* __restrict__ idx, float* __restrict__ out, int N) {
    int m = blockIdx.x;
    int c = idx[m];
    int n0 = (blockIdx.y * blockDim.x + threadIdx.x) * 4;
    if (n0 >= N) return;
    v4f b = *reinterpret_cast<const v4f*>(base + n0);
    v4f r;
    r.x = b.x - pre[(size_t)(n0 + 0) * CE_C + c];
    r.y = b.y - pre[(size_t)(n0 + 1) * CE_C + c];
    r.z = b.z - pre[(size_t)(n0 + 2) * CE_C + c];
    r.w = b.w - pre[(size_t)(n0 + 3) * CE_C + c];
    *reinterpret_cast<v4f*>(out + (size_t)m * N + n0) = r;
}

extern "C" void kernel_launch(void* const* d_in, const int* in_sizes, int n_in,
                              void* d_out, int out_size, void* d_ws, size_t ws_size,
                              hipStream_t stream) {
    const int* idx  = (const int*)d_in[0];     // gt_kind_ind, int32 [M]
    const float* pre = (const float*)d_in[1];  // pre_cls, f32 [N, C]
    float* out = (float*)d_out;                // f32 [M, N]

    const int M = in_sizes[0];
    const int N = in_sizes[1] / CE_C;

    if ((N % TN) == 0 && (M % TM) == 0) {
        dim3 grid(N / TN, M / TM);             // 32 x 8 = 256 blocks
        ce_fused<<<grid, 512, 0, stream>>>(pre, idx, out, N);
    } else {
        // fallback still uses a tiny base[] scratch in d_ws (N floats)
        const int block = 256;
        const int chunks = (N + 4 * block - 1) / (4 * block);
        float* base = (float*)d_ws;
        ce_base<<<(N + block - 1) / block, block, 0, stream>>>(pre, base, N);
        dim3 grid(M, chunks);
        ce_direct<<<grid, block, 0, stream>>>(pre, base, idx, out, N);
    }
}

// Round 4
// 287.064 us; speedup vs baseline: 1.0333x; 1.0333x over previous
//
#include <hip/hip_runtime.h>
#include <math.h>

// out[m, n] = base[n] - pre_cls[n, idx[m]],  base[n] = sum_c softplus(pre_cls[n, c])
// M = N = 8192, C = 80.
//
// R4: class-bucketed scatter.
// Model from R2/R3 counters: timed window = ~213 us unconditional harness
// poison (1 GiB ws fill ~170 us + 268 MB out fill ~43 us) + our kernels
// (R2 ~62 us, floor ~46 us). To close the last gap, make the store stream
// load-free: bucket rows by class, then each block loads its D-row chunk
// ONCE into registers and streams NT float4 stores to all rows of that
// class (fill-kernel structure, 6.27 TB/s demonstrated).

#define CE_C 80

typedef float v4f __attribute__((ext_vector_type(4)));

__device__ __forceinline__ float softplus_f(float x) {
    // logaddexp(x, 0) = max(x,0) + log1p(exp(-|x|))
    return fmaxf(x, 0.0f) + log1pf(expf(-fabsf(x)));
}

// ---- ce_prep (R2-verified): D[c][n] = base[n] - pre[n][c], 2.6 MB in ws ----
// 4 threads per n; block of 256 covers 64 n's; each part handles 20 classes.
__global__ __launch_bounds__(256) void ce_prep(const float* __restrict__ pre,
                                               float* __restrict__ D, int N) {
    int t = threadIdx.x;
    int n = blockIdx.x * 64 + (t >> 2);
    if (n >= N) return;
    int part = t & 3;
    const float* row = pre + (size_t)n * CE_C + part * 20;
    v4f v[5];
    float s = 0.0f;
#pragma unroll
    for (int j = 0; j < 5; ++j) {
        v[j] = *reinterpret_cast<const v4f*>(row + j * 4);
        s += softplus_f(v[j].x) + softplus_f(v[j].y)
           + softplus_f(v[j].z) + softplus_f(v[j].w);
    }
    s += __shfl_xor(s, 1);
    s += __shfl_xor(s, 2);
    int c0 = part * 20;
#pragma unroll
    for (int j = 0; j < 5; ++j) {
        float* d0 = D + (size_t)(c0 + j * 4) * N + n;
        d0[0]             = s - v[j].x;
        d0[(size_t)N]     = s - v[j].y;
        d0[2 * (size_t)N] = s - v[j].z;
        d0[3 * (size_t)N] = s - v[j].w;
    }
}

// ---- ce_lists: bucket the M row indices by class. One block (self-synced). ----
__global__ __launch_bounds__(1024) void ce_lists(const int* __restrict__ idx,
                                                 int* __restrict__ starts,   // [C+1]
                                                 int* __restrict__ list,     // [M]
                                                 int M) {
    __shared__ int scnt[CE_C];
    __shared__ int soff[CE_C];
    int t = threadIdx.x;
    if (t < CE_C) scnt[t] = 0;
    __syncthreads();
    for (int m = t; m < M; m += 1024)
        atomicAdd(&scnt[idx[m]], 1);
    __syncthreads();
    if (t == 0) {
        int acc = 0;
        for (int c = 0; c < CE_C; ++c) { soff[c] = acc; acc += scnt[c]; }
    }
    __syncthreads();
    if (t < CE_C) starts[t] = soff[t];    // read soff BEFORE pass-2 mutates it
    if (t == 0) starts[CE_C] = M;
    __syncthreads();
    for (int m = t; m < M; m += 1024) {
        int pos = atomicAdd(&soff[idx[m]], 1);
        list[pos] = m;                    // order within a class is irrelevant
    }
}

// ---- ce_scatter: grid (C, N/2048, 4), block 256. ----
// Block owns (class c, 2048-col chunk, quarter of c's row list).
// Loads 2 float4 of D once into regs, then pure NT stores to ~len/4 rows.
__global__ __launch_bounds__(256) void ce_scatter(const float* __restrict__ D,
                                                  const int* __restrict__ starts,
                                                  const int* __restrict__ list,
                                                  float* __restrict__ out, int N) {
    int c = blockIdx.x;
    int col0 = blockIdx.y * 2048;
    int q = blockIdx.z;
    int s = starts[c], e = starts[c + 1];
    int len = e - s;
    int b0 = s + ((len * q) >> 2);
    int b1 = s + ((len * (q + 1)) >> 2);
    if (b0 >= b1) return;
    int t = threadIdx.x;
    const v4f* drow = (const v4f*)(D + (size_t)c * N + col0);
    v4f d0 = drow[t];
    v4f d1 = drow[t + 256];
    __shared__ int lm[256];
    for (int base = b0; base < b1; base += 256) {
        int cnt = min(256, b1 - base);
        __syncthreads();                          // protect lm reuse
        if (t < cnt) lm[t] = list[base + t];
        __syncthreads();
        for (int i = 0; i < cnt; ++i) {
            int m = lm[i];                        // LDS broadcast
            v4f* dst = (v4f*)(out + (size_t)m * N + col0);
            __builtin_nontemporal_store(d0, dst + t);
            __builtin_nontemporal_store(d1, dst + t + 256);
        }
    }
}

// ---- generic fallback (no/odd shapes or tiny ws): base-only path ----
__global__ void ce_base(const float* __restrict__ pre, float* __restrict__ base, int N) {
    int n = blockIdx.x * blockDim.x + threadIdx.x;
    if (n >= N) return;
    const float* row = pre + (size_t)n * CE_C;
    float b = 0.0f;
#pragma unroll
    for (int c = 0; c < CE_C; c += 4) {
        v4f v = *reinterpret_cast<const v4f*>(row + c);
        b += softplus_f(v.x) + softplus_f(v.y) + softplus_f(v.z) + softplus_f(v.w);
    }
    base[n] = b;
}

__global__ void ce_direct(const float* __restrict__ pre, const float* __restrict__ base,
                          const int* __restrict__ idx, float* __restrict__ out, int N) {
    int m = blockIdx.x;
    int c = idx[m];
    int n0 = (blockIdx.y * blockDim.x + threadIdx.x) * 4;
    if (n0 >= N) return;
    v4f b = *reinterpret_cast<const v4f*>(base + n0);
    v4f r;
    r.x = b.x - pre[(size_t)(n0 + 0) * CE_C + c];
    r.y = b.y - pre[(size_t)(n0 + 1) * CE_C + c];
    r.z = b.z - pre[(size_t)(n0 + 2) * CE_C + c];
    r.w = b.w - pre[(size_t)(n0 + 3) * CE_C + c];
    *reinterpret_cast<v4f*>(out + (size_t)m * N + n0) = r;
}

extern "C" void kernel_launch(void* const* d_in, const int* in_sizes, int n_in,
                              void* d_out, int out_size, void* d_ws, size_t ws_size,
                              hipStream_t stream) {
    const int* idx  = (const int*)d_in[0];     // gt_kind_ind, int32 [M]
    const float* pre = (const float*)d_in[1];  // pre_cls, f32 [N, C]
    float* out = (float*)d_out;                // f32 [M, N]

    const int M = in_sizes[0];
    const int N = in_sizes[1] / CE_C;

    const size_t D_bytes   = (size_t)CE_C * (size_t)N * sizeof(float);
    const size_t starts_off = D_bytes;                 // 81 ints
    const size_t list_off   = D_bytes + 512;           // padded
    const size_t need       = list_off + (size_t)M * sizeof(int);

    if (ws_size >= need && (N % 2048) == 0 && (N % 64) == 0) {
        float* D     = (float*)d_ws;
        int* starts  = (int*)((char*)d_ws + starts_off);
        int* list    = (int*)((char*)d_ws + list_off);
        ce_prep<<<(N + 63) / 64, 256, 0, stream>>>(pre, D, N);
        ce_lists<<<1, 1024, 0, stream>>>(idx, starts, list, M);
        dim3 grid(CE_C, N / 2048, 4);                  // 80 x 4 x 4 = 1280 blocks
        ce_scatter<<<grid, 256, 0, stream>>>(D, starts, list, out, N);
    } else {
        const int block = 256;
        const int chunks = (N + 4 * block - 1) / (4 * block);
        float* base = (float*)d_ws;                    // N floats
        ce_base<<<(N + block - 1) / block, block, 0, stream>>>(pre, base, N);
        dim3 grid(M, chunks);
        ce_direct<<<grid, block, 0, stream>>>(pre, base, idx, out, N);
    }
}

// Round 5
// 277.035 us; speedup vs baseline: 1.0707x; 1.0362x over previous
//
#include <hip/hip_runtime.h>
#include <math.h>

// out[m, n] = base[n] - pre_cls[n, idx[m]],  base[n] = sum_c softplus(pre_cls[n, c])
// M = N = 8192, C = 80.
//
// R5: back to the R2 structure (best measured: 275.8 us) — D table in ws +
// row-gather with NT stores. Post-mortems:
//   R3 fused (296.6): scalar 4B stores, low wave count — worse.
//   R4 scatter (287.1): load-free stores but class imbalance + serial list
//     build + 80 interleaved scattered write streams — worse.
// Model: ~213 us unconditional harness poison (fills run even when ws is
// untouched) + kernel part. R2 kernel part ~62 us vs ~50-56 us floor
// (268 MB mandatory write at the fill-demonstrated 6.3 TB/s + launch).
// R5's single change: gather blocks 4x fatter (4 rows / 1024 threads) to
// cut block count 8192->2048 and quadruple independent row streams per
// block. If this lands within noise of 275.8, we are at the roofline.

#define CE_C 80

typedef float v4f __attribute__((ext_vector_type(4)));

__device__ __forceinline__ float softplus_f(float x) {
    // logaddexp(x, 0) = max(x,0) + log1p(exp(-|x|))
    return fmaxf(x, 0.0f) + log1pf(expf(-fabsf(x)));
}

// ---- ce_prep (R2-verified): D[c][n] = base[n] - pre[n][c], 2.6 MB in ws ----
// 4 threads per n; block of 256 covers 64 n's; each part handles 20 classes.
__global__ __launch_bounds__(256) void ce_prep(const float* __restrict__ pre,
                                               float* __restrict__ D, int N) {
    int t = threadIdx.x;
    int n = blockIdx.x * 64 + (t >> 2);
    if (n >= N) return;
    int part = t & 3;
    const float* row = pre + (size_t)n * CE_C + part * 20;
    v4f v[5];
    float s = 0.0f;
#pragma unroll
    for (int j = 0; j < 5; ++j) {
        v[j] = *reinterpret_cast<const v4f*>(row + j * 4);
        s += softplus_f(v[j].x) + softplus_f(v[j].y)
           + softplus_f(v[j].z) + softplus_f(v[j].w);
    }
    s += __shfl_xor(s, 1);
    s += __shfl_xor(s, 2);
    int c0 = part * 20;
#pragma unroll
    for (int j = 0; j < 5; ++j) {
        float* d0 = D + (size_t)(c0 + j * 4) * N + n;
        d0[0]             = s - v[j].x;
        d0[(size_t)N]     = s - v[j].y;
        d0[2 * (size_t)N] = s - v[j].z;
        d0[3 * (size_t)N] = s - v[j].w;
    }
}

// ---- ce_gather: 4 rows per 1024-thread block. ----
// Thread t handles row (t>>8) of the block's 4, column segment (t&255).
// idx[m] is uniform within each wave -> scalar load. 8 float4 loads (L2 hit
// on D) batched before 8 NT float4 stores (out is write-only).
__global__ __launch_bounds__(1024) void ce_gather(const float* __restrict__ D,
                                                  const int* __restrict__ idx,
                                                  float* __restrict__ out, int N) {
    int r = threadIdx.x >> 8;                 // 0..3
    int t = threadIdx.x & 255;                // 0..255
    long m = (long)blockIdx.x * 4 + r;
    int c = idx[m];                           // wave-uniform -> scalar load
    const v4f* __restrict__ src = reinterpret_cast<const v4f*>(D + (size_t)c * N);
    v4f* __restrict__ dst = reinterpret_cast<v4f*>(out + (size_t)m * N);
    v4f v[8];
#pragma unroll
    for (int k = 0; k < 8; ++k) v[k] = src[t + k * 256];
#pragma unroll
    for (int k = 0; k < 8; ++k) __builtin_nontemporal_store(v[k], &dst[t + k * 256]);
}

// generic-shape gather (N not multiple of 8192/2048 path)
__global__ __launch_bounds__(256) void ce_gather_gen(const float* __restrict__ D,
                                                     const int* __restrict__ idx,
                                                     float* __restrict__ out, int N) {
    int m = blockIdx.x;
    int c = idx[m];
    const float* src = D + (size_t)c * N;
    float* dst = out + (size_t)m * N;
    for (int i = threadIdx.x; i < N; i += 256)
        __builtin_nontemporal_store(src[i], &dst[i]);
}

// ---- fallback path (workspace too small for D): base only (32 KB) ----
__global__ void ce_base(const float* __restrict__ pre, float* __restrict__ base, int N) {
    int n = blockIdx.x * blockDim.x + threadIdx.x;
    if (n >= N) return;
    const float* row = pre + (size_t)n * CE_C;
    float b = 0.0f;
#pragma unroll
    for (int c = 0; c < CE_C; c += 4) {
        v4f v = *reinterpret_cast<const v4f*>(row + c);
        b += softplus_f(v.x) + softplus_f(v.y) + softplus_f(v.z) + softplus_f(v.w);
    }
    base[n] = b;
}

__global__ void ce_direct(const float* __restrict__ pre, const float* __restrict__ base,
                          const int* __restrict__ idx, float* __restrict__ out, int N) {
    int m = blockIdx.x;
    int c = idx[m];
    int n0 = (blockIdx.y * blockDim.x + threadIdx.x) * 4;
    if (n0 >= N) return;
    v4f b = *reinterpret_cast<const v4f*>(base + n0);
    v4f r;
    r.x = b.x - pre[(size_t)(n0 + 0) * CE_C + c];
    r.y = b.y - pre[(size_t)(n0 + 1) * CE_C + c];
    r.z = b.z - pre[(size_t)(n0 + 2) * CE_C + c];
    r.w = b.w - pre[(size_t)(n0 + 3) * CE_C + c];
    *reinterpret_cast<v4f*>(out + (size_t)m * N + n0) = r;
}

extern "C" void kernel_launch(void* const* d_in, const int* in_sizes, int n_in,
                              void* d_out, int out_size, void* d_ws, size_t ws_size,
                              hipStream_t stream) {
    const int* idx  = (const int*)d_in[0];     // gt_kind_ind, int32 [M]
    const float* pre = (const float*)d_in[1];  // pre_cls, f32 [N, C]
    float* out = (float*)d_out;                // f32 [M, N]

    const int M = in_sizes[0];
    const int N = in_sizes[1] / CE_C;

    const size_t needD = (size_t)CE_C * (size_t)N * sizeof(float);

    if (ws_size >= needD && (N % 64) == 0) {
        float* D = (float*)d_ws;
        ce_prep<<<(N + 63) / 64, 256, 0, stream>>>(pre, D, N);
        if (N == 8192 && (M % 4) == 0) {
            ce_gather<<<M / 4, 1024, 0, stream>>>(D, idx, out, N);
        } else {
            ce_gather_gen<<<M, 256, 0, stream>>>(D, idx, out, N);
        }
    } else {
        const int block = 256;
        const int chunks = (N + 4 * block - 1) / (4 * block);
        float* base = (float*)d_ws;            // N floats
        ce_base<<<(N + block - 1) / block, block, 0, stream>>>(pre, base, N);
        dim3 grid(M, chunks);
        ce_direct<<<grid, block, 0, stream>>>(pre, base, idx, out, N);
    }
}